// Round 3
// baseline (273.936 us; speedup 1.0000x reference)
//
#include <hip/hip_runtime.h>
#include <hip/hip_bf16.h>

// X = Z * G, G = (I - tril(A_raw,-1))^{-1} (unit lower-triangular 256x256)
// Z: [131072 x 256] fp32, Out: [131072 x 256] fp32.
//
// make_G3 (unchanged): 256 blocks, right-looking solve, readlane broadcast.
// scm_gemm6: full-iteration software pipeline, this time FORCED:
//   - amdgpu_waves_per_eu(4,4): LDS caps us at 2 blocks/CU = 4 waves/SIMD
//     anyway; telling the scheduler max=4 unlocks the 128-VGPR budget so the
//     16-float4 rotation stays in registers (R2 evidence: without it the
//     scheduler targeted 8 waves/EU, emitted 64 VGPR, and sank all loads to
//     their packs -> latency-bound at 34% HBM).
//   - sched_barrier(0x38F) after each kk sub-block: ALU/VALU/SALU/MFMA/DS may
//     cross, VMEM may NOT -> loads for iter i+1 stay issued in iter i, one
//     full iteration (~56 MFMAs) ahead of their consumer. Stores are newer
//     than the loads being waited on, so load-waits never drain stores.
//   - plain stores (nontemporal inflated WRITE_SIZE 131.5->139 MB in R2).

typedef __bf16 bf16x8 __attribute__((ext_vector_type(8)));
typedef float f32x4 __attribute__((ext_vector_type(4)));

__device__ __forceinline__ unsigned short f2bf(float f) {
    union { float f; unsigned u; } v; v.f = f;
    unsigned u = v.u;
    u += 0x7FFFu + ((u >> 16) & 1u);   // RNE
    return (unsigned short)(u >> 16);
}
__device__ __forceinline__ bf16x8 pack8(float4 a, float4 b) {
    union { bf16x8 v; __hip_bfloat162 h[4]; } u;
    u.h[0] = __float22bfloat162_rn(make_float2(a.x, a.y));
    u.h[1] = __float22bfloat162_rn(make_float2(a.z, a.w));
    u.h[2] = __float22bfloat162_rn(make_float2(b.x, b.y));
    u.h[3] = __float22bfloat162_rn(make_float2(b.z, b.w));
    return u.v;
}

// ---------------------------------------------------------------------------
// Kernel 1: G columns, one block per column (unchanged).
// ---------------------------------------------------------------------------
#define AST 258
__global__ __launch_bounds__(256) void make_G3(const float* __restrict__ A,
                                               unsigned short* __restrict__ Gt) {
    __shared__ unsigned short As[256 * AST];   // 129 KB
    const int tid = threadIdx.x;
    const int l = tid & 63;
    const int wv = tid >> 6;

    for (int it = 0; it < 64; ++it) {
        const int r = it * 4 + wv;
        const int c0 = l * 4;
        float4 v = *(const float4*)(A + r * 256 + c0);
        *(ushort2*)(&As[r * AST + c0])     = make_ushort2(f2bf(v.x), f2bf(v.y));
        *(ushort2*)(&As[r * AST + c0 + 2]) = make_ushort2(f2bf(v.z), f2bf(v.w));
    }
    __syncthreads();
    if (wv != 0) return;

    const int c = blockIdx.x;
    float p[4];
#pragma unroll
    for (int k = 0; k < 4; ++k) p[k] = (64 * k + l == c) ? 1.f : 0.f;

#pragma unroll
    for (int kb = 0; kb < 4; ++kb) {
#pragma unroll 8
        for (int i2 = 0; i2 < 32; ++i2) {
            unsigned u[4];
#pragma unroll
            for (int k = 0; k < 4; ++k)
                if (k >= kb)
                    u[k] = *(const unsigned*)(&As[(64 * k + l) * AST + kb * 64 + 2 * i2]);
            const int t0 = 2 * i2, t1 = t0 + 1;
            float s0 = __int_as_float(__builtin_amdgcn_readlane(__float_as_int(p[kb]), t0));
            p[kb] += (l > t0 ? __int_as_float(u[kb] << 16) : 0.f) * s0;
#pragma unroll
            for (int k = 0; k < 4; ++k)
                if (k > kb) p[k] += __int_as_float(u[k] << 16) * s0;
            float s1 = __int_as_float(__builtin_amdgcn_readlane(__float_as_int(p[kb]), t1));
            p[kb] += (l > t1 ? __int_as_float(u[kb] & 0xffff0000u) : 0.f) * s1;
#pragma unroll
            for (int k = 0; k < 4; ++k)
                if (k > kb) p[k] += __int_as_float(u[k] & 0xffff0000u) * s1;
        }
    }
#pragma unroll
    for (int k = 0; k < 4; ++k)
        Gt[c * 256 + 64 * k + l] = f2bf(p[k]);
}

// ---------------------------------------------------------------------------
// Kernel 2: Out = Z @ G. 512 blocks (256 M-tiles x 2 N-halves) x 512 thr.
// ---------------------------------------------------------------------------
#define SBAR() __builtin_amdgcn_sched_barrier(0x38F) /* pin VMEM only */

__global__ __launch_bounds__(512)
__attribute__((amdgpu_waves_per_eu(4, 4)))
void scm_gemm6(const float* __restrict__ Z,
               const unsigned short* __restrict__ Gt,
               float* __restrict__ Out) {
    __shared__ __align__(16) unsigned short Gs[128 * 256];   // 64 KB
    const int tid = threadIdx.x;
    const int lane = tid & 63;
    const int wave = tid >> 6;
    const int n = lane & 15;
    const int quad = lane >> 4;
    // Blocks m and m+256 read identical Z rows; 256 apart -> same XCD slot,
    // and all 512 blocks are co-resident (2/CU) -> 2nd Z read is cache-hot.
    const int bn = (blockIdx.x >> 8) * 128;
    const size_t blockRow = (size_t)(blockIdx.x & 255) * 512;

    // ---- stage G half (64 KB): 4096 granules / 512 thr = 8 each ----
#pragma unroll
    for (int it = 0; it < 8; ++it) {
        const int chunk = it * 512 + tid;
        const int row = chunk >> 5;            // local col 0..127
        const int g = chunk & 31;
        const int gs = g ^ (row & 7);
        uint4 v = *(const uint4*)(Gt + (bn + row) * 256 + g * 8);
        *(uint4*)(&Gs[row * 256 + gs * 8]) = v;
    }
    __syncthreads();

    const int swz = n & 7;
    const float* zbase = Z + (blockRow + wave * 16 + n) * 256 + quad * 8;
    float* obase = Out + (blockRow + wave * 16 + quad * 4) * 256 + bn + n;

    f32x4 acc[8];
#pragma unroll
    for (int nt = 0; nt < 8; ++nt) {
        f32x4 zero = {0.f, 0.f, 0.f, 0.f};
        acc[nt] = zero;
    }

    // Full-iteration prefetch buffers: zA = K-lo half, zB = K-hi half.
    float4 zA[8], zB[8];
#pragma unroll
    for (int kk = 0; kk < 4; ++kk) {
        zA[2 * kk]     = *(const float4*)(zbase + kk * 32);
        zA[2 * kk + 1] = *(const float4*)(zbase + kk * 32 + 4);
    }
#pragma unroll
    for (int kk = 0; kk < 4; ++kk) {
        zB[2 * kk]     = *(const float4*)(zbase + 128 + kk * 32);
        zB[2 * kk + 1] = *(const float4*)(zbase + 128 + kk * 32 + 4);
    }

#pragma unroll
    for (int i = 0; i < 4; ++i) {
        const bool pf = (i < 3);
        const float* zn = zbase + (size_t)((i < 3) ? (i + 1) : 0) * 128 * 256;

        // ---- K-lo: pack (waits loads issued 1 iter ago), reload freed regs
        //      for iter i+1, 8 MFMAs, then fence VMEM movement ----
#pragma unroll
        for (int kk = 0; kk < 4; ++kk) {
            bf16x8 af = pack8(zA[2 * kk], zA[2 * kk + 1]);
            if (pf) {
                zA[2 * kk]     = *(const float4*)(zn + kk * 32);
                zA[2 * kk + 1] = *(const float4*)(zn + kk * 32 + 4);
            }
#pragma unroll
            for (int nt = 0; nt < 8; ++nt) {
                const bf16x8 b = *(const bf16x8*)(
                    &Gs[(nt * 16 + n) * 256 + ((kk * 4 + quad) ^ swz) * 8]);
                acc[nt] = __builtin_amdgcn_mfma_f32_16x16x32_bf16(af, b, acc[nt], 0, 0, 0);
            }
            SBAR();
        }
        // ---- K-hi ----
#pragma unroll
        for (int kk = 0; kk < 4; ++kk) {
            bf16x8 af = pack8(zB[2 * kk], zB[2 * kk + 1]);
            if (pf) {
                zB[2 * kk]     = *(const float4*)(zn + 128 + kk * 32);
                zB[2 * kk + 1] = *(const float4*)(zn + 128 + kk * 32 + 4);
            }
#pragma unroll
            for (int nt = 0; nt < 8; ++nt) {
                const bf16x8 b = *(const bf16x8*)(
                    &Gs[(nt * 16 + n) * 256 + ((16 + kk * 4 + quad) ^ swz) * 8]);
                acc[nt] = __builtin_amdgcn_mfma_f32_16x16x32_bf16(af, b, acc[nt], 0, 0, 0);
            }
            SBAR();
        }
        // ---- store + re-zero. C/D layout: col = lane&15, row = quad*4 + r.
        float* oi = obase + (size_t)i * 128 * 256;
#pragma unroll
        for (int nt = 0; nt < 8; ++nt)
#pragma unroll
            for (int r = 0; r < 4; ++r) {
                oi[(size_t)r * 256 + nt * 16] = acc[nt][r];
                acc[nt][r] = 0.f;
            }
    }
}

extern "C" void kernel_launch(void* const* d_in, const int* in_sizes, int n_in,
                              void* d_out, int out_size, void* d_ws, size_t ws_size,
                              hipStream_t stream) {
    const float* Z = (const float*)d_in[0];       // [131072 x 256]
    const float* A = (const float*)d_in[1];       // [256 x 256]
    float* Out = (float*)d_out;                   // [131072 x 256]
    unsigned short* Gt = (unsigned short*)d_ws;   // 256*256 bf16 = 128 KB

    hipLaunchKernelGGL(make_G3, dim3(256), dim3(256), 0, stream, A, Gt);
    hipLaunchKernelGGL(scm_gemm6, dim3(512), dim3(512), 0, stream, Z, Gt, Out);
}

// Round 6
// 266.694 us; speedup vs baseline: 1.0272x; 1.0272x over previous
//
#include <hip/hip_runtime.h>
#include <hip/hip_bf16.h>

// X = Z * G, G = (I - tril(A_raw,-1))^{-1} (unit lower-triangular 256x256)
// Z: [131072 x 256] fp32, Out: [131072 x 256] fp32.
//
// make_G3 (unchanged): 256 blocks, right-looking solve, readlane broadcast.
// scm_gemm8: gemm4 geometry (512 blocks = 256 M x 2 N-halves, 512 thr, 64 KB
//   Gs, XOR swizzle) + asm-forced DISTANCE-4 pipeline (R5's distance-8 needed
//   ~148 VGPR -> spill -> scratch VMEM corrupted the vmcnt counts AND spilled
//   in-flight load destinations -> wrong results).
//   32 linear phases t (4 iters x 8). zf[] = 4 float4-pairs cycling period 4:
//   phase t consumes the pair issued at t-4, reissues the slot for t+4.
//   Counted waits (retirement is in TOTAL VMEM issue order, stores included):
//     prologue 8 loads; iter0: vmcnt(6) all phases;
//     steady: subphase 0-3 -> 38 (32-store block between pair-issue and wait),
//             subphase 4-7 -> 6;  tail t=29,30,31 -> 4,2,0.
//   Stores are only awaited >=4 phases after issue (plus one final vmcnt(0)).
//   Peak regs ~116 < 128 cap of __launch_bounds__(512,4) -> no spill.

typedef __bf16 bf16x8 __attribute__((ext_vector_type(8)));
typedef float f32x4 __attribute__((ext_vector_type(4)));

__device__ __forceinline__ unsigned short f2bf(float f) {
    union { float f; unsigned u; } v; v.f = f;
    unsigned u = v.u;
    u += 0x7FFFu + ((u >> 16) & 1u);   // RNE
    return (unsigned short)(u >> 16);
}
__device__ __forceinline__ bf16x8 pack8(float4 a, float4 b) {
    union { bf16x8 v; __hip_bfloat162 h[4]; } u;
    u.h[0] = __float22bfloat162_rn(make_float2(a.x, a.y));
    u.h[1] = __float22bfloat162_rn(make_float2(a.z, a.w));
    u.h[2] = __float22bfloat162_rn(make_float2(b.x, b.y));
    u.h[3] = __float22bfloat162_rn(make_float2(b.z, b.w));
    return u.v;
}

// ---------------------------------------------------------------------------
// Kernel 1: G columns, one block per column (unchanged).
// ---------------------------------------------------------------------------
#define AST 258
__global__ __launch_bounds__(256) void make_G3(const float* __restrict__ A,
                                               unsigned short* __restrict__ Gt) {
    __shared__ unsigned short As[256 * AST];   // 129 KB
    const int tid = threadIdx.x;
    const int l = tid & 63;
    const int wv = tid >> 6;

    for (int it = 0; it < 64; ++it) {
        const int r = it * 4 + wv;
        const int c0 = l * 4;
        float4 v = *(const float4*)(A + r * 256 + c0);
        *(ushort2*)(&As[r * AST + c0])     = make_ushort2(f2bf(v.x), f2bf(v.y));
        *(ushort2*)(&As[r * AST + c0 + 2]) = make_ushort2(f2bf(v.z), f2bf(v.w));
    }
    __syncthreads();
    if (wv != 0) return;

    const int c = blockIdx.x;
    float p[4];
#pragma unroll
    for (int k = 0; k < 4; ++k) p[k] = (64 * k + l == c) ? 1.f : 0.f;

#pragma unroll
    for (int kb = 0; kb < 4; ++kb) {
#pragma unroll 8
        for (int i2 = 0; i2 < 32; ++i2) {
            unsigned u[4];
#pragma unroll
            for (int k = 0; k < 4; ++k)
                if (k >= kb)
                    u[k] = *(const unsigned*)(&As[(64 * k + l) * AST + kb * 64 + 2 * i2]);
            const int t0 = 2 * i2, t1 = t0 + 1;
            float s0 = __int_as_float(__builtin_amdgcn_readlane(__float_as_int(p[kb]), t0));
            p[kb] += (l > t0 ? __int_as_float(u[kb] << 16) : 0.f) * s0;
#pragma unroll
            for (int k = 0; k < 4; ++k)
                if (k > kb) p[k] += __int_as_float(u[k] << 16) * s0;
            float s1 = __int_as_float(__builtin_amdgcn_readlane(__float_as_int(p[kb]), t1));
            p[kb] += (l > t1 ? __int_as_float(u[kb] & 0xffff0000u) : 0.f) * s1;
#pragma unroll
            for (int k = 0; k < 4; ++k)
                if (k > kb) p[k] += __int_as_float(u[k] & 0xffff0000u) * s1;
        }
    }
#pragma unroll
    for (int k = 0; k < 4; ++k)
        Gt[c * 256 + 64 * k + l] = f2bf(p[k]);
}

// ---------------------------------------------------------------------------
// Kernel 2: Out = Z @ G, asm-pipelined, distance-4.
// ---------------------------------------------------------------------------
// Linear phase T (0..31): iter = T>>3, sub-phase q = T&7, pair p = T&3.
// Consumes pair p (loaded at phase T-4 / prologue); prefetches for T+4.
template<int T>
__device__ __forceinline__ void phaseT(float4& a0, float4& a1,
                                       const float* zbase, f32x4 acc[8],
                                       const unsigned short* Gsp,
                                       int n, int quad, int swz) {
    constexpr int q = T & 7;
    constexpr int CNT = (T < 8)   ? 6
                      : (T == 29) ? 4
                      : (T == 30) ? 2
                      : (T == 31) ? 0
                      : (q < 4 ? 38 : 6);
    asm volatile("s_waitcnt vmcnt(%0)" :: "n"(CNT) : "memory");
    __builtin_amdgcn_sched_barrier(0);           // pin pack/MFMA below wait
    bf16x8 af = pack8(a0, a1);
    if constexpr (T + 4 < 32) {
        constexpr int TT = T + 4;
        const float* pz = zbase + (size_t)(TT >> 3) * 32768;
        asm volatile("global_load_dwordx4 %0, %1, off offset:%2"
                     : "=v"(a0) : "v"(pz), "n"((TT & 7) * 128));
        asm volatile("global_load_dwordx4 %0, %1, off offset:%2"
                     : "=v"(a1) : "v"(pz), "n"((TT & 7) * 128 + 16));
    }
#pragma unroll
    for (int nt = 0; nt < 8; ++nt) {
        const bf16x8 b = *(const bf16x8*)(
            &Gsp[(nt * 16 + n) * 256 + ((q * 4 + quad) ^ swz) * 8]);
        acc[nt] = __builtin_amdgcn_mfma_f32_16x16x32_bf16(af, b, acc[nt], 0, 0, 0);
    }
}

__global__ __launch_bounds__(512, 4) void scm_gemm8(const float* __restrict__ Z,
                                                    const unsigned short* __restrict__ Gt,
                                                    float* __restrict__ Out) {
    __shared__ __align__(16) unsigned short Gs[128 * 256];   // 64 KB
    const int tid = threadIdx.x;
    const int lane = tid & 63;
    const int wave = tid >> 6;
    const int n = lane & 15;
    const int quad = lane >> 4;
    const int bn = (blockIdx.x & 1) * 128;                 // gemm4 mapping
    const size_t blockRow = (size_t)(blockIdx.x >> 1) * 512;

    // ---- stage G half (64 KB): 4096 granules / 512 thr = 8 each ----
#pragma unroll
    for (int it = 0; it < 8; ++it) {
        const int chunk = it * 512 + tid;
        const int row = chunk >> 5;            // local col 0..127
        const int g = chunk & 31;
        const int gs = g ^ (row & 7);
        uint4 v = *(const uint4*)(Gt + (bn + row) * 256 + g * 8);
        *(uint4*)(&Gs[row * 256 + gs * 8]) = v;
    }
    __syncthreads();   // compiler drains vmcnt/lgkmcnt here -> outstanding = 0

    const int swz = n & 7;
    const float* zbase = Z + (blockRow + wave * 16 + n) * 256 + quad * 8;
    float* obase = Out + (blockRow + wave * 16 + quad * 4) * 256 + bn + n;

    f32x4 acc[8];
#pragma unroll
    for (int nt = 0; nt < 8; ++nt) {
        f32x4 zero = {0.f, 0.f, 0.f, 0.f};
        acc[nt] = zero;
    }

    // 4 pairs = 8 float4 = 32 VGPR rotation buffer.
    float4 zf[8];
    // ---- prologue: pairs for phases 0..3 (iter 0, k-granule groups 0..3) ----
    asm volatile("global_load_dwordx4 %0, %1, off offset:0"   : "=v"(zf[0]) : "v"(zbase));
    asm volatile("global_load_dwordx4 %0, %1, off offset:16"  : "=v"(zf[1]) : "v"(zbase));
    asm volatile("global_load_dwordx4 %0, %1, off offset:128" : "=v"(zf[2]) : "v"(zbase));
    asm volatile("global_load_dwordx4 %0, %1, off offset:144" : "=v"(zf[3]) : "v"(zbase));
    asm volatile("global_load_dwordx4 %0, %1, off offset:256" : "=v"(zf[4]) : "v"(zbase));
    asm volatile("global_load_dwordx4 %0, %1, off offset:272" : "=v"(zf[5]) : "v"(zbase));
    asm volatile("global_load_dwordx4 %0, %1, off offset:384" : "=v"(zf[6]) : "v"(zbase));
    asm volatile("global_load_dwordx4 %0, %1, off offset:400" : "=v"(zf[7]) : "v"(zbase));

#define PH(T) phaseT<T>(zf[2 * ((T) & 3)], zf[2 * ((T) & 3) + 1], zbase, acc, Gs, n, quad, swz)
#define STORE_ITER(i, REZERO)                                              \
    {                                                                      \
        asm volatile("" ::: "memory");                                     \
        float* oi = obase + (size_t)(i) * 32768;                           \
        _Pragma("unroll")                                                  \
        for (int nt = 0; nt < 8; ++nt)                                     \
            _Pragma("unroll")                                              \
            for (int r = 0; r < 4; ++r) {                                  \
                oi[(size_t)r * 256 + nt * 16] = acc[nt][r];                \
                if (REZERO) acc[nt][r] = 0.f;                              \
            }                                                              \
        asm volatile("" ::: "memory");                                     \
    }

    PH(0);  PH(1);  PH(2);  PH(3);  PH(4);  PH(5);  PH(6);  PH(7);
    STORE_ITER(0, true);
    PH(8);  PH(9);  PH(10); PH(11); PH(12); PH(13); PH(14); PH(15);
    STORE_ITER(1, true);
    PH(16); PH(17); PH(18); PH(19); PH(20); PH(21); PH(22); PH(23);
    STORE_ITER(2, true);
    PH(24); PH(25); PH(26); PH(27); PH(28); PH(29); PH(30); PH(31);
    STORE_ITER(3, false);

#undef PH
#undef STORE_ITER
}

extern "C" void kernel_launch(void* const* d_in, const int* in_sizes, int n_in,
                              void* d_out, int out_size, void* d_ws, size_t ws_size,
                              hipStream_t stream) {
    const float* Z = (const float*)d_in[0];       // [131072 x 256]
    const float* A = (const float*)d_in[1];       // [256 x 256]
    float* Out = (float*)d_out;                   // [131072 x 256]
    unsigned short* Gt = (unsigned short*)d_ws;   // 256*256 bf16 = 128 KB

    hipLaunchKernelGGL(make_G3, dim3(256), dim3(256), 0, stream, A, Gt);
    hipLaunchKernelGGL(scm_gemm8, dim3(512), dim3(512), 0, stream, Z, Gt, Out);
}